// Round 7
// baseline (277.613 us; speedup 1.0000x reference)
//
#include <hip/hip_runtime.h>

typedef short v8s __attribute__((ext_vector_type(8)));
typedef float v4f __attribute__((ext_vector_type(4)));

#define Wh   1024
#define HWh  (1024 * 512)
#define Wlr  512
#define HWlr (512 * 256)

#define THREADS 1024
#define WAVES   16
#define NBLK    256
#define MAXIT   4         // 16 waves * 4 iters * 32 px = 2048 px per block

// Activation buffer: fragment-major B-operand layout, in-place, wave-private.
// element (px, ch): half = px>>4, frag = ch>>5, lane' = ((ch>>3)&3)*16 + (px&15), off = ch&7
#define HALF_STRIDE 2048               // 4 frags * 512 shorts, no pad (2-way conflicts only)
#define ACT_SHORTS  (2 * HALF_STRIDE)  // 4096 shorts = 8192 B per wave
#define WF_N         31                // W0 frags 0..30 in LDS; frag 31 + W1..W3 in d_ws
#define WFRAG_SHORTS (WF_N * 512)
#define LDS_BYTES   ((WFRAG_SHORTS + WAVES * ACT_SHORTS) * 2)  // 31744 + 131072 = 162816

// d_ws layout (shorts): frag 0 = W0[mt=7][ks=3]; 1..16 = W1; 17..20 = W2; 21 = W3
#define WS_FRAGS 22

__device__ __forceinline__ unsigned short f2bf(float f) {
    union { float f; unsigned u; } v; v.f = f;
    unsigned r = v.u + 0x7FFFu + ((v.u >> 16) & 1u);  // RNE (cold paths only)
    return (unsigned short)(r >> 16);
}
// hot-path pack: round-half-up bias + v_perm grabbing the two high halves (3 VALU)
__device__ __forceinline__ unsigned pk2(float a, float b) {
    union { float f; unsigned u; } ua, ub;
    ua.f = a; ub.f = b;
    return __builtin_amdgcn_perm(ub.u + 0x8000u, ua.u + 0x8000u, 0x07060302u);
}
__device__ __forceinline__ float leaky(float x) { return fmaxf(x, 0.01f * x); }

// epilogue write: channels c0..c0+3 (c0 = 16*mt + 4*q) of pixel p, half h
__device__ __forceinline__ void ep_write(unsigned short* buf, int h, int c0, int p, uint2 v) {
    *(uint2*)(buf + h * HALF_STRIDE + (c0 >> 5) * 512 +
              (((c0 >> 3) & 3) * 16 + p) * 8 + (c0 & 7)) = v;
}
// staging write: rep component c (frag c), channels 8*pass+4*cq .. +3, pixel px
__device__ __forceinline__ void stq(unsigned short* buf, int px, int pass, int cq,
                                    int c, unsigned lo, unsigned hi) {
    *(uint2*)(buf + (px >> 4) * HALF_STRIDE + c * 512 +
              (pass * 16 + (px & 15)) * 8 + 4 * cq) = (uint2){lo, hi};
}

// ---------- prep kernel: convert small weights to bf16 A-fragments in d_ws ----------
__global__ void prep_kernel(const float* __restrict__ w0g, const float* __restrict__ w1g,
                            const float* __restrict__ w2g, const float* __restrict__ w3g,
                            unsigned short* __restrict__ ws)
{
    const int f = blockIdx.x;          // 0..21
    const int l = threadIdx.x;         // 0..63
    const int pp = l & 15, qq = l >> 4;
    const float* src;
    if (f == 0)       src = w0g + (7 * 16 + pp) * 128 + 3 * 32 + qq * 8;       // W0 frag 31
    else if (f < 17)  { int g = f - 1;  src = w1g + ((g >> 2) * 16 + pp) * 128 + (g & 3) * 32 + qq * 8; }
    else if (f < 21)  { int g = f - 17; src = w2g + ((g >> 1) * 16 + pp) * 64  + (g & 1) * 32 + qq * 8; }
    else              src = w3g + pp * 32 + qq * 8;                            // W3
    unsigned short* dst = ws + f * 512 + l * 8;
#pragma unroll
    for (int j = 0; j < 8; ++j) dst[j] = f2bf(src[j]);
}

// ---------- main kernel ----------
__global__ __launch_bounds__(THREADS, 4)
void cmfsm_kernel(const float* __restrict__ lr, const float* __restrict__ hr,
                  const float* __restrict__ w0g, const float* __restrict__ w4g,
                  const float* __restrict__ w5g, const float* __restrict__ t0g,
                  const float* __restrict__ t1g, const float* __restrict__ t2g,
                  const float* __restrict__ fwg, const unsigned short* __restrict__ wsf,
                  float* __restrict__ out)
{
    extern __shared__ unsigned short smem[];
    unsigned short* wfrag = smem;                    // W0 frags 0..30, lane-contiguous
    unsigned short* actS  = smem + WFRAG_SHORTS;

    const int tid  = threadIdx.x;
    const int lane = tid & 63;
    const int wv   = tid >> 6;
    const int p    = lane & 15;   // MFMA n within a 16-px tile
    const int q    = lane >> 4;   // MFMA k-quad
    const int px   = lane & 31;   // staging pixel
    const int cq   = lane >> 5;   // staging channel-quad selector

    // ---- stage W0 frags 0..30 into LDS ----
    for (int e = tid; e < WF_N * 64; e += THREADS) {
        int f = e >> 6, l = e & 63;
        int mt = f >> 2, ks = f & 3, pp = l & 15, qq = l >> 4;
        const float* src = w0g + (mt * 16 + pp) * 128 + ks * 32 + qq * 8;
        unsigned short* dst = wfrag + f * 512 + l * 8;
#pragma unroll
        for (int j = 0; j < 8; ++j) dst[j] = f2bf(src[j]);
    }

    // ---- fused layers 4+5: w45[r] = sum_j w5[j]*w4[j][4q+r] ----
    float w45[4];
#pragma unroll
    for (int r = 0; r < 4; ++r) {
        float s = 0.f;
#pragma unroll
        for (int j = 0; j < 8; ++j) s += w5g[j] * w4g[j * 16 + q * 4 + r];
        w45[r] = s;
    }

    // ---- weights2: 4 parity values ----
    float w2tab[4];
#pragma unroll
    for (int yp = 0; yp < 2; ++yp)
#pragma unroll
        for (int xp = 0; xp < 2; ++xp) {
            float i0 = xp ? 1.f : -1.f;
            float i1 = yp ? 1.f : -1.f;
            float i2 = 1.41421356237309505f;
            float h0[3], h1[2];
            for (int o = 0; o < 3; ++o)
                h0[o] = leaky(t0g[o*3+0]*i0 + t0g[o*3+1]*i1 + t0g[o*3+2]*i2);
            for (int o = 0; o < 2; ++o)
                h1[o] = leaky(t1g[o*3+0]*h0[0] + t1g[o*3+1]*h0[1] + t1g[o*3+2]*h0[2]);
            w2tab[yp*2+xp] = t2g[0]*h1[0] + t2g[1]*h1[1];
        }
    const float fa = fabsf(fwg[0]);
    const float fb = fabsf(fwg[1]);

    const unsigned short* wsl = wsf + lane * 8;   // this lane's slice of each ws frag

    __syncthreads();   // wfrag ready; act buffers are wave-private hereafter

    unsigned short* B = actS + wv * ACT_SHORTS;
    const v4f z4 = (v4f){0.f, 0.f, 0.f, 0.f};

#pragma unroll 1
    for (int it = 0; it < MAXIT; ++it) {
        const int gbase = ((blockIdx.x * MAXIT + it) * WAVES + wv) * 32;  // wave-uniform
        const int y     = gbase >> 10;
        const float* hr_it = hr + gbase;                        // + ch*HWh + px
        const float* lr_it = lr + (y >> 1) * Wlr + ((gbase & 1023) >> 1);

        // ---- stage rep: 4 passes, each lane 4 consecutive channels of 1 px (b64 writes) ----
#pragma unroll
        for (int pass = 0; pass < 4; ++pass) {
            const int ch = pass * 8 + cq * 4;
            float h0 = hr_it[(size_t)(ch + 0) * HWh + px];
            float h1 = hr_it[(size_t)(ch + 1) * HWh + px];
            float h2 = hr_it[(size_t)(ch + 2) * HWh + px];
            float h3 = hr_it[(size_t)(ch + 3) * HWh + px];
            float l0 = lr_it[(size_t)(ch + 0) * HWlr + (px >> 1)];
            float l1 = lr_it[(size_t)(ch + 1) * HWlr + (px >> 1)];
            float l2 = lr_it[(size_t)(ch + 2) * HWlr + (px >> 1)];
            float l3 = lr_it[(size_t)(ch + 3) * HWlr + (px >> 1)];
            stq(B, px, pass, cq, 0, pk2(l0, l1), pk2(l2, l3));                  // lr_up
            stq(B, px, pass, cq, 1, pk2(h0, h1), pk2(h2, h3));                  // hr
            stq(B, px, pass, cq, 2, pk2(l0*h0, l1*h1), pk2(l2*h2, l3*h3));      // product
            float d0 = l0-h0, d1 = l1-h1, d2 = l2-h2, d3 = l3-h3;
            stq(B, px, pass, cq, 3, pk2(d0*d0, d1*d1), pk2(d2*d2, d3*d3));      // sq diff
        }

        // ---- layer 0: 128 -> 128, b-frags cached in regs (in-place safe) ----
        {
            v8s bfr[4][2];
#pragma unroll
            for (int ks = 0; ks < 4; ++ks) {
                bfr[ks][0] = *(const v8s*)(B + ks * 512 + lane * 8);
                bfr[ks][1] = *(const v8s*)(B + HALF_STRIDE + ks * 512 + lane * 8);
            }
            v8s w0f31 = *(const v8s*)(wsl + 0 * 512);   // frag 31 from L2
#pragma unroll
            for (int mh = 0; mh < 2; ++mh) {
                v4f acc[4][2];
#pragma unroll
                for (int ks = 0; ks < 4; ++ks)
#pragma unroll
                    for (int mi = 0; mi < 4; ++mi) {
                        const int f = (mh * 4 + mi) * 4 + ks;
                        v8s a = (f == 31) ? w0f31
                                          : *(const v8s*)(wfrag + f * 512 + lane * 8);
                        acc[mi][0] = __builtin_amdgcn_mfma_f32_16x16x32_bf16(
                            a, bfr[ks][0], ks == 0 ? z4 : acc[mi][0], 0, 0, 0);
                        acc[mi][1] = __builtin_amdgcn_mfma_f32_16x16x32_bf16(
                            a, bfr[ks][1], ks == 0 ? z4 : acc[mi][1], 0, 0, 0);
                    }
#pragma unroll
                for (int mi = 0; mi < 4; ++mi) {
                    const int c0 = 16 * (mh * 4 + mi) + 4 * q;
#pragma unroll
                    for (int h = 0; h < 2; ++h) {
                        uint2 v;
                        v.x = pk2(leaky(acc[mi][h][0]), leaky(acc[mi][h][1]));
                        v.y = pk2(leaky(acc[mi][h][2]), leaky(acc[mi][h][3]));
                        ep_write(B, h, c0, p, v);
                    }
                }
            }
        }

        // ---- layer 1: 128 -> 64, W1 a-frags from L2 (ws frags 1..16) ----
        {
            v8s bfr[4][2];
#pragma unroll
            for (int ks = 0; ks < 4; ++ks) {
                bfr[ks][0] = *(const v8s*)(B + ks * 512 + lane * 8);
                bfr[ks][1] = *(const v8s*)(B + HALF_STRIDE + ks * 512 + lane * 8);
            }
            v4f acc[4][2];
#pragma unroll
            for (int ks = 0; ks < 4; ++ks) {
                v8s a0 = *(const v8s*)(wsl + (1 + 0 * 4 + ks) * 512);
                v8s a1 = *(const v8s*)(wsl + (1 + 1 * 4 + ks) * 512);
                v8s a2 = *(const v8s*)(wsl + (1 + 2 * 4 + ks) * 512);
                v8s a3 = *(const v8s*)(wsl + (1 + 3 * 4 + ks) * 512);
#pragma unroll
                for (int h = 0; h < 2; ++h) {
                    acc[0][h] = __builtin_amdgcn_mfma_f32_16x16x32_bf16(a0, bfr[ks][h], ks == 0 ? z4 : acc[0][h], 0, 0, 0);
                    acc[1][h] = __builtin_amdgcn_mfma_f32_16x16x32_bf16(a1, bfr[ks][h], ks == 0 ? z4 : acc[1][h], 0, 0, 0);
                    acc[2][h] = __builtin_amdgcn_mfma_f32_16x16x32_bf16(a2, bfr[ks][h], ks == 0 ? z4 : acc[2][h], 0, 0, 0);
                    acc[3][h] = __builtin_amdgcn_mfma_f32_16x16x32_bf16(a3, bfr[ks][h], ks == 0 ? z4 : acc[3][h], 0, 0, 0);
                }
            }
#pragma unroll
            for (int mt = 0; mt < 4; ++mt) {
                const int c0 = 16 * mt + 4 * q;
#pragma unroll
                for (int h = 0; h < 2; ++h) {
                    uint2 v;
                    v.x = pk2(leaky(acc[mt][h][0]), leaky(acc[mt][h][1]));
                    v.y = pk2(leaky(acc[mt][h][2]), leaky(acc[mt][h][3]));
                    ep_write(B, h, c0, p, v);
                }
            }
        }

        // ---- layer 2: 64 -> 32, W2 a-frags from L2 (ws frags 17..20) ----
        {
            v8s bfr[2][2];
#pragma unroll
            for (int ks = 0; ks < 2; ++ks) {
                bfr[ks][0] = *(const v8s*)(B + ks * 512 + lane * 8);
                bfr[ks][1] = *(const v8s*)(B + HALF_STRIDE + ks * 512 + lane * 8);
            }
            v4f acc[2][2];
#pragma unroll
            for (int ks = 0; ks < 2; ++ks) {
                v8s a0 = *(const v8s*)(wsl + (17 + 0 * 2 + ks) * 512);
                v8s a1 = *(const v8s*)(wsl + (17 + 1 * 2 + ks) * 512);
#pragma unroll
                for (int h = 0; h < 2; ++h) {
                    acc[0][h] = __builtin_amdgcn_mfma_f32_16x16x32_bf16(a0, bfr[ks][h], ks == 0 ? z4 : acc[0][h], 0, 0, 0);
                    acc[1][h] = __builtin_amdgcn_mfma_f32_16x16x32_bf16(a1, bfr[ks][h], ks == 0 ? z4 : acc[1][h], 0, 0, 0);
                }
            }
#pragma unroll
            for (int mt = 0; mt < 2; ++mt) {
                const int c0 = 16 * mt + 4 * q;
#pragma unroll
                for (int h = 0; h < 2; ++h) {
                    uint2 v;
                    v.x = pk2(leaky(acc[mt][h][0]), leaky(acc[mt][h][1]));
                    v.y = pk2(leaky(acc[mt][h][2]), leaky(acc[mt][h][3]));
                    ep_write(B, h, c0, p, v);
                }
            }
        }

        // ---- layer 3: 32 -> 16 (ws frag 21), fused 16->8->1, fuse with weights2 ----
        {
            v8s a = *(const v8s*)(wsl + 21 * 512);
            float res[2];
#pragma unroll
            for (int h = 0; h < 2; ++h) {
                v8s b = *(const v8s*)(B + h * HALF_STRIDE + lane * 8);
                v4f acc3 = __builtin_amdgcn_mfma_f32_16x16x32_bf16(a, b, z4, 0, 0, 0);
                float part = 0.f;
#pragma unroll
                for (int r = 0; r < 4; ++r) part += w45[r] * leaky(acc3[r]);
                part += __shfl_xor(part, 16, 64);
                part += __shfl_xor(part, 32, 64);
                res[h] = part;
            }
            const float wb = fb * w2tab[((y & 1) << 1) | (p & 1)];
            if (q == 0)      out[gbase + p]      = fa * res[0] + wb;
            else if (q == 1) out[gbase + 16 + p] = fa * res[1] + wb;
        }
    }
}

extern "C" void kernel_launch(void* const* d_in, const int* in_sizes, int n_in,
                              void* d_out, int out_size, void* d_ws, size_t ws_size,
                              hipStream_t stream) {
    const float* lr  = (const float*)d_in[0];
    const float* hr  = (const float*)d_in[1];
    const float* w0g = (const float*)d_in[2];
    const float* w1g = (const float*)d_in[3];
    const float* w2g = (const float*)d_in[4];
    const float* w3g = (const float*)d_in[5];
    const float* w4g = (const float*)d_in[6];
    const float* w5g = (const float*)d_in[7];
    const float* t0g = (const float*)d_in[8];
    const float* t1g = (const float*)d_in[9];
    const float* t2g = (const float*)d_in[10];
    const float* fwg = (const float*)d_in[11];
    float* out = (float*)d_out;
    unsigned short* wsf = (unsigned short*)d_ws;

    hipLaunchKernelGGL(prep_kernel, dim3(WS_FRAGS), dim3(64), 0, stream,
                       w0g, w1g, w2g, w3g, wsf);
    hipLaunchKernelGGL(cmfsm_kernel, dim3(NBLK), dim3(THREADS), LDS_BYTES, stream,
                       lr, hr, w0g, w4g, w5g, t0g, t1g, t2g, fwg, wsf, out);
}

// Round 8
// 149.238 us; speedup vs baseline: 1.8602x; 1.8602x over previous
//
#include <hip/hip_runtime.h>

typedef short v8s __attribute__((ext_vector_type(8)));
typedef float v4f __attribute__((ext_vector_type(4)));

#define Wh   1024
#define Hh   512
#define HWh  (Wh * Hh)
#define Wlr  512
#define HWlr (Wlr * 256)
#define PAD  136          // act row stride in shorts (272 B) -> 2-way max on B-frag reads
#define ITERS 8
#define NBLK  256         // 256 blocks x 16 waves x 8 iters x 16 px = 524288 px

// LDS layout (shorts):
//   wfrag[53*512]  : 53 fragments (W0:32, W1:16, W2:4, W3:1), lane-contiguous 16B frags
//   actS[16][16*PAD]: per-wave private activation buffer (16 px x 128 ch + pad)
#define WFRAG_SHORTS (53 * 512)
#define ACT_SHORTS   (16 * PAD)
#define LDS_BYTES    ((WFRAG_SHORTS + 16 * ACT_SHORTS) * 2)   // 54272 + 69632 = 123904

__device__ __forceinline__ unsigned short f2bf(float f) {
    union { float f; unsigned u; } v; v.f = f;
    unsigned r = v.u + 0x7FFFu + ((v.u >> 16) & 1u);  // RNE (cold paths only)
    return (unsigned short)(r >> 16);
}
// hot-path pack: round-half-up bias + v_perm grabbing the two high halves (3 VALU)
__device__ __forceinline__ unsigned pk2(float a, float b) {
    union { float f; unsigned u; } ua, ub;
    ua.f = a; ub.f = b;
    return __builtin_amdgcn_perm(ub.u + 0x8000u, ua.u + 0x8000u, 0x07060302u);
}
__device__ __forceinline__ float leaky(float x) { return fmaxf(x, 0.01f * x); }

// issue the 16 staging loads for the 16-px group at gbase (per-lane: 2 ch of hr pair + lr pair x4)
__device__ __forceinline__ void ld16(const float* __restrict__ hr, const float* __restrict__ lr,
                                     int gbase, int p, int q,
                                     float (&h)[4][2], float (&l)[4][2]) {
    const int y  = gbase >> 10;
    const int xg = (gbase & 1023) + p;
    const float* hb = hr + (size_t)y * Wh + xg;
    const float* lb = lr + (size_t)(y >> 1) * Wlr + (xg >> 1);
#pragma unroll
    for (int pass = 0; pass < 4; ++pass) {
        const int ch = pass * 8 + q * 2;
        h[pass][0] = hb[(size_t)ch * HWh];
        h[pass][1] = hb[(size_t)(ch + 1) * HWh];
        l[pass][0] = lb[(size_t)ch * HWlr];
        l[pass][1] = lb[(size_t)(ch + 1) * HWlr];
    }
}

__global__ __launch_bounds__(1024, 4)
void cmfsm_kernel(const float* __restrict__ lr, const float* __restrict__ hr,
                  const float* __restrict__ w0g, const float* __restrict__ w1g,
                  const float* __restrict__ w2g, const float* __restrict__ w3g,
                  const float* __restrict__ w4g, const float* __restrict__ w5g,
                  const float* __restrict__ t0g, const float* __restrict__ t1g,
                  const float* __restrict__ t2g, const float* __restrict__ fwg,
                  float* __restrict__ out)
{
    extern __shared__ unsigned short smem[];
    unsigned short* wfrag = smem;                    // 53*512 shorts
    unsigned short* actS  = smem + WFRAG_SHORTS;

    const int tid  = threadIdx.x;
    const int lane = tid & 63;
    const int wv   = tid >> 6;
    const int p    = lane & 15;   // MFMA n (pixel)
    const int q    = lane >> 4;   // MFMA k-quad

    // ---- stage weights as A-fragments into LDS, fragment-major ----
    for (int e = tid; e < 32 * 64; e += 1024) {
        int f = e >> 6, l = e & 63;
        int mt = f >> 2, ks = f & 3, pp = l & 15, qq = l >> 4;
        const float* src = w0g + (mt * 16 + pp) * 128 + ks * 32 + qq * 8;
        unsigned short* dst = wfrag + f * 512 + l * 8;
#pragma unroll
        for (int j = 0; j < 8; ++j) dst[j] = f2bf(src[j]);
    }
    if (tid < 16 * 64) {
        int f = tid >> 6, l = tid & 63;
        int mt = f >> 2, ks = f & 3, pp = l & 15, qq = l >> 4;
        const float* src = w1g + (mt * 16 + pp) * 128 + ks * 32 + qq * 8;
        unsigned short* dst = wfrag + (32 + f) * 512 + l * 8;
#pragma unroll
        for (int j = 0; j < 8; ++j) dst[j] = f2bf(src[j]);
    }
    if (tid < 4 * 64) {
        int f = tid >> 6, l = tid & 63;
        int mt = f >> 1, ks = f & 1, pp = l & 15, qq = l >> 4;
        const float* src = w2g + (mt * 16 + pp) * 64 + ks * 32 + qq * 8;
        unsigned short* dst = wfrag + (48 + f) * 512 + l * 8;
#pragma unroll
        for (int j = 0; j < 8; ++j) dst[j] = f2bf(src[j]);
    }
    if (tid < 64) {
        int l = tid;
        int pp = l & 15, qq = l >> 4;
        const float* src = w3g + pp * 32 + qq * 8;
        unsigned short* dst = wfrag + 52 * 512 + l * 8;
#pragma unroll
        for (int j = 0; j < 8; ++j) dst[j] = f2bf(src[j]);
    }

    // ---- fused linear layers 4+5: w45[r] = sum_j w5[j]*w4[j][4q+r] ----
    float w45[4];
#pragma unroll
    for (int r = 0; r < 4; ++r) {
        float s = 0.f;
#pragma unroll
        for (int j = 0; j < 8; ++j) s += w5g[j] * w4g[j * 16 + q * 4 + r];
        w45[r] = s;
    }

    // ---- weights2: only 4 parity values ----
    float w2tab[4];
#pragma unroll
    for (int yp = 0; yp < 2; ++yp)
#pragma unroll
        for (int xp = 0; xp < 2; ++xp) {
            float i0 = xp ? 1.f : -1.f;
            float i1 = yp ? 1.f : -1.f;
            float i2 = 1.41421356237309505f;
            float h0[3], h1[2];
            for (int o = 0; o < 3; ++o)
                h0[o] = leaky(t0g[o*3+0]*i0 + t0g[o*3+1]*i1 + t0g[o*3+2]*i2);
            for (int o = 0; o < 2; ++o)
                h1[o] = leaky(t1g[o*3+0]*h0[0] + t1g[o*3+1]*h0[1] + t1g[o*3+2]*h0[2]);
            w2tab[yp*2+xp] = t2g[0]*h1[0] + t2g[1]*h1[1];
        }
    const float fa = fabsf(fwg[0]);
    const float fb = fabsf(fwg[1]);

    __syncthreads();   // wfrag ready; everything after is wave-private

    unsigned short* A = actS + wv * ACT_SHORTS;

    // ---- software pipeline: preload iteration 0's 16 staging values ----
    float ph[4][2], pl[4][2];
    ld16(hr, lr, (blockIdx.x * ITERS) * 256 + wv * 16, p, q, ph, pl);

#pragma unroll 1
    for (int it = 0; it < ITERS; ++it) {
        const int gbase = (blockIdx.x * ITERS + it) * 256 + wv * 16;  // 16 consecutive px
        const int y     = gbase >> 10;
        const int xg    = (gbase & 1023) + p;

        // ---- build rep[p][0..127] in LDS from prefetched registers ----
#pragma unroll
        for (int pass = 0; pass < 4; ++pass) {
            int ch = pass * 8 + q * 2;
            float h0 = ph[pass][0], h1 = ph[pass][1];
            float l0 = pl[pass][0], l1 = pl[pass][1];
            unsigned* Ap = (unsigned*)(A + p * PAD);
            Ap[ch >> 1]        = pk2(l0, l1);            // lr_up
            Ap[(32 + ch) >> 1] = pk2(h0, h1);            // hr
            Ap[(64 + ch) >> 1] = pk2(l0 * h0, l1 * h1);  // product
            float d0 = l0 - h0, d1 = l1 - h1;
            Ap[(96 + ch) >> 1] = pk2(d0 * d0, d1 * d1);  // squared diff
        }

        // ---- issue next iteration's staging loads (overlap HBM latency with layers) ----
        const int nit = (it + 1 < ITERS) ? it + 1 : it;
        ld16(hr, lr, (blockIdx.x * ITERS + nit) * 256 + wv * 16, p, q, ph, pl);

        // ---- layer 0: 128 -> 128 ----
        v4f acc0[8];
#pragma unroll
        for (int mt = 0; mt < 8; ++mt) acc0[mt] = (v4f){0.f, 0.f, 0.f, 0.f};
#pragma unroll
        for (int ks = 0; ks < 4; ++ks) {
            v8s b = *(const v8s*)(A + p * PAD + ks * 32 + q * 8);
#pragma unroll
            for (int mt = 0; mt < 8; ++mt) {
                v8s a = *(const v8s*)(wfrag + (mt * 4 + ks) * 512 + lane * 8);
                acc0[mt] = __builtin_amdgcn_mfma_f32_16x16x32_bf16(a, b, acc0[mt], 0, 0, 0);
            }
        }
#pragma unroll
        for (int mt = 0; mt < 8; ++mt) {
            uint2 v;
            v.x = pk2(leaky(acc0[mt][0]), leaky(acc0[mt][1]));
            v.y = pk2(leaky(acc0[mt][2]), leaky(acc0[mt][3]));
            *(uint2*)(A + p * PAD + mt * 16 + q * 4) = v;   // act[p][16mt+4q+r]
        }

        // ---- layer 1: 128 -> 64 ----
        v4f acc1[4];
#pragma unroll
        for (int mt = 0; mt < 4; ++mt) acc1[mt] = (v4f){0.f, 0.f, 0.f, 0.f};
#pragma unroll
        for (int ks = 0; ks < 4; ++ks) {
            v8s b = *(const v8s*)(A + p * PAD + ks * 32 + q * 8);
#pragma unroll
            for (int mt = 0; mt < 4; ++mt) {
                v8s a = *(const v8s*)(wfrag + (32 + mt * 4 + ks) * 512 + lane * 8);
                acc1[mt] = __builtin_amdgcn_mfma_f32_16x16x32_bf16(a, b, acc1[mt], 0, 0, 0);
            }
        }
#pragma unroll
        for (int mt = 0; mt < 4; ++mt) {
            uint2 v;
            v.x = pk2(leaky(acc1[mt][0]), leaky(acc1[mt][1]));
            v.y = pk2(leaky(acc1[mt][2]), leaky(acc1[mt][3]));
            *(uint2*)(A + p * PAD + mt * 16 + q * 4) = v;
        }

        // ---- layer 2: 64 -> 32 ----
        v4f acc2[2];
#pragma unroll
        for (int mt = 0; mt < 2; ++mt) acc2[mt] = (v4f){0.f, 0.f, 0.f, 0.f};
#pragma unroll
        for (int ks = 0; ks < 2; ++ks) {
            v8s b = *(const v8s*)(A + p * PAD + ks * 32 + q * 8);
#pragma unroll
            for (int mt = 0; mt < 2; ++mt) {
                v8s a = *(const v8s*)(wfrag + (48 + mt * 2 + ks) * 512 + lane * 8);
                acc2[mt] = __builtin_amdgcn_mfma_f32_16x16x32_bf16(a, b, acc2[mt], 0, 0, 0);
            }
        }
#pragma unroll
        for (int mt = 0; mt < 2; ++mt) {
            uint2 v;
            v.x = pk2(leaky(acc2[mt][0]), leaky(acc2[mt][1]));
            v.y = pk2(leaky(acc2[mt][2]), leaky(acc2[mt][3]));
            *(uint2*)(A + p * PAD + mt * 16 + q * 4) = v;
        }

        // ---- layer 3: 32 -> 16, fused 16->8->1, fuse with weights2 ----
        {
            v8s b = *(const v8s*)(A + p * PAD + q * 8);
            v8s a = *(const v8s*)(wfrag + 52 * 512 + lane * 8);
            v4f acc3 = __builtin_amdgcn_mfma_f32_16x16x32_bf16(a, b, (v4f){0.f, 0.f, 0.f, 0.f}, 0, 0, 0);

            float part = 0.f;
#pragma unroll
            for (int r = 0; r < 4; ++r) part += w45[r] * leaky(acc3[r]);
            part += __shfl_xor(part, 16, 64);
            part += __shfl_xor(part, 32, 64);

            if (q == 0) {
                float res = fa * part + fb * w2tab[(y & 1) * 2 + (xg & 1)];
                out[y * Wh + xg] = res;
            }
        }
    }
}

extern "C" void kernel_launch(void* const* d_in, const int* in_sizes, int n_in,
                              void* d_out, int out_size, void* d_ws, size_t ws_size,
                              hipStream_t stream) {
    const float* lr  = (const float*)d_in[0];
    const float* hr  = (const float*)d_in[1];
    const float* w0g = (const float*)d_in[2];
    const float* w1g = (const float*)d_in[3];
    const float* w2g = (const float*)d_in[4];
    const float* w3g = (const float*)d_in[5];
    const float* w4g = (const float*)d_in[6];
    const float* w5g = (const float*)d_in[7];
    const float* t0g = (const float*)d_in[8];
    const float* t1g = (const float*)d_in[9];
    const float* t2g = (const float*)d_in[10];
    const float* fwg = (const float*)d_in[11];
    float* out = (float*)d_out;

    hipLaunchKernelGGL(cmfsm_kernel, dim3(NBLK), dim3(1024), LDS_BYTES, stream,
                       lr, hr, w0g, w1g, w2g, w3g, w4g, w5g, t0g, t1g, t2g, fwg, out);
}